// Round 3
// baseline (583.594 us; speedup 1.0000x reference)
//
#include <hip/hip_runtime.h>

// FFF tree-routing MLP, MI355X — fp32 I/O. Round 3: phase-split + leaf-sort.
//
// R2 post-mortem: fused kernel was latency-bound (VGPR=224 -> 2 waves/SIMD,
// Occupancy 11%, VALUBusy 8%). Split into:
//   K1 transpose w_out -> w_out_T (64x64 tiles, 16 elem/thread)
//   K2 phaseA: per-token wave, path + gelu(logits) only (low VGPR -> high occ)
//   K3-K5 sort tokens by leaf (hist/scan/scatter) -- tokens at same leaf share
//        the entire 12-node path => w_out gather traffic /4
//   K6 phaseB: block per leaf, 8 cols/thread, chunks of <=8 tokens, no
//        dependent chain -> runs at cache BW.

#define D_IN    2048
#define D_OUT   2048
#define DEPTHP1 12
#define N_NODES 4095
#define N_TOK   8192
#define N_LEAF  2048

// ---------------- K1: transpose w_out [D_OUT, N_NODES] -> [N_NODES, D_OUT] --
__global__ __launch_bounds__(256) void transpose_wout64(
    const float* __restrict__ in, float* __restrict__ out) {
    __shared__ float tile[64][65];
    const int n0 = blockIdx.x * 64;
    const int j0 = blockIdx.y * 64;
    const int tx = threadIdx.x;       // 0..63
    const int ty = threadIdx.y;       // 0..3
    const int n = n0 + tx;
#pragma unroll
    for (int k = 0; k < 16; k++) {
        const int r = ty * 16 + k;    // 0..63
        if (n < N_NODES) tile[r][tx] = in[(size_t)(j0 + r) * N_NODES + n];
    }
    __syncthreads();
#pragma unroll
    for (int k = 0; k < 16; k++) {
        const int r = ty * 16 + k;
        const int nn = n0 + r;
        if (nn < N_NODES) out[(size_t)nn * D_OUT + (j0 + tx)] = tile[tx][r];
    }
}

// ---------------- K2: phase A — path + gelu(logit) per token ---------------
__global__ __launch_bounds__(256, 4) void phaseA(
    const float* __restrict__ x,      // [N_TOK, D_IN]
    const float* __restrict__ w_in,   // [N_NODES, D_IN]
    float* __restrict__ g_all,        // [N_TOK, 12]
    int* __restrict__ leaf,           // [N_TOK]
    int* __restrict__ hist) {         // [N_LEAF]
    const int wave  = threadIdx.x >> 6;
    const int lane  = threadIdx.x & 63;
    const int token = blockIdx.x * 4 + wave;

    const float4* xrow = (const float4*)(x + (size_t)token * D_IN);
    float xf[32];
#pragma unroll
    for (int c = 0; c < 8; c++) {
        float4 xc = xrow[lane + 64 * c];
        xf[c * 4 + 0] = xc.x;
        xf[c * 4 + 1] = xc.y;
        xf[c * 4 + 2] = xc.z;
        xf[c * 4 + 3] = xc.w;
    }

    int cur = 0;
    int leafid = 0;
#pragma unroll
    for (int l = 0; l < DEPTHP1; l++) {
        const float4* wrow = (const float4*)(w_in + (size_t)cur * D_IN);
        float part = 0.f;
#pragma unroll
        for (int c = 0; c < 8; c++) {
            float4 wc = wrow[lane + 64 * c];
            part += wc.x * xf[c * 4 + 0];
            part += wc.y * xf[c * 4 + 1];
            part += wc.z * xf[c * 4 + 2];
            part += wc.w * xf[c * 4 + 3];
        }
#pragma unroll
        for (int off = 32; off >= 1; off >>= 1)
            part += __shfl_xor(part, off, 64);
        const float score = part;
        const float g = 0.5f * score * (1.0f + erff(score * 0.70710678118654752f));
        if (lane == 0) g_all[token * DEPTHP1 + l] = g;
        if (l == DEPTHP1 - 1) leafid = cur - (N_LEAF - 1);  // cur in [2047,4094]
        cur = 2 * cur + 1 + (score >= 0.f ? 1 : 0);
    }
    if (lane == 0) {
        leaf[token] = leafid;
        atomicAdd(&hist[leafid], 1);
    }
}

// ---------------- K3: zero hist + cnt (contiguous 2*N_LEAF ints) -----------
__global__ __launch_bounds__(256) void init_counts(int* __restrict__ p) {
    const int i = blockIdx.x * 256 + threadIdx.x;
    if (i < 2 * N_LEAF) p[i] = 0;
}

// ---------------- K4: exclusive scan over 2048 bins ------------------------
__global__ __launch_bounds__(256) void scan2048(
    const int* __restrict__ hist, int* __restrict__ offsets /*[2049]*/) {
    __shared__ int vals[N_LEAF];
    __shared__ int partial[256];
    const int t = threadIdx.x;
    int sum = 0;
#pragma unroll
    for (int k = 0; k < 8; k++) {
        const int v = hist[t * 8 + k];
        vals[t * 8 + k] = v;
        sum += v;
    }
    partial[t] = sum;
    __syncthreads();
    for (int off = 1; off < 256; off <<= 1) {
        const int v  = partial[t];
        const int vo = (t >= off) ? partial[t - off] : 0;
        __syncthreads();
        partial[t] = v + vo;
        __syncthreads();
    }
    int base = (t > 0) ? partial[t - 1] : 0;
#pragma unroll
    for (int k = 0; k < 8; k++) {
        offsets[t * 8 + k] = base;
        base += vals[t * 8 + k];
    }
    if (t == 255) offsets[N_LEAF] = base;  // == N_TOK
}

// ---------------- K5: scatter token ids into leaf-sorted order -------------
__global__ __launch_bounds__(256) void scatter_tokens(
    const int* __restrict__ leaf, const int* __restrict__ offsets,
    int* __restrict__ cnt, int* __restrict__ order) {
    const int t = blockIdx.x * 256 + threadIdx.x;
    if (t < N_TOK) {
        const int lf = leaf[t];
        const int pos = offsets[lf] + atomicAdd(&cnt[lf], 1);
        order[pos] = t;
    }
}

// ---------------- K6: phase B — leaf-grouped output accumulation -----------
__global__ __launch_bounds__(256, 4) void phaseB(
    const float* __restrict__ w_out_t,  // [N_NODES, D_OUT]
    const float* __restrict__ g_all,    // [N_TOK, 12]
    const int* __restrict__ order,      // [N_TOK]
    const int* __restrict__ offsets,    // [N_LEAF+1]
    float* __restrict__ out) {          // [N_TOK, D_OUT]
    const int lf = blockIdx.x;
    const int start = offsets[lf];
    const int end   = offsets[lf + 1];
    if (start == end) return;
    const int t = threadIdx.x;           // owns cols [8t, 8t+8)

    int nodes[DEPTHP1];
    const int L = lf + N_LEAF;           // 1-based leaf heap index
#pragma unroll
    for (int l = 0; l < DEPTHP1; l++) nodes[l] = (L >> (DEPTHP1 - 1 - l)) - 1;

    for (int cs = start; cs < end; cs += 8) {
        const int T = min(8, end - cs);
        int toks[8];
#pragma unroll
        for (int tt = 0; tt < 8; tt++)
            toks[tt] = (tt < T) ? order[cs + tt] : 0;
        float acc[8][8];
#pragma unroll
        for (int tt = 0; tt < 8; tt++)
#pragma unroll
            for (int k = 0; k < 8; k++) acc[tt][k] = 0.f;

#pragma unroll
        for (int l = 0; l < DEPTHP1; l++) {
            const float4* wr = (const float4*)(w_out_t + (size_t)nodes[l] * D_OUT);
            const float4 w0 = wr[t * 2 + 0];
            const float4 w1 = wr[t * 2 + 1];
            for (int tt = 0; tt < T; tt++) {
                const float g = g_all[toks[tt] * DEPTHP1 + l];
                acc[tt][0] += g * w0.x; acc[tt][1] += g * w0.y;
                acc[tt][2] += g * w0.z; acc[tt][3] += g * w0.w;
                acc[tt][4] += g * w1.x; acc[tt][5] += g * w1.y;
                acc[tt][6] += g * w1.z; acc[tt][7] += g * w1.w;
            }
        }
        for (int tt = 0; tt < T; tt++) {
            float4* po = (float4*)(out + (size_t)toks[tt] * D_OUT + t * 8);
            float4 o0, o1;
            o0.x = acc[tt][0]; o0.y = acc[tt][1]; o0.z = acc[tt][2]; o0.w = acc[tt][3];
            o1.x = acc[tt][4]; o1.y = acc[tt][5]; o1.z = acc[tt][6]; o1.w = acc[tt][7];
            po[0] = o0; po[1] = o1;
        }
    }
}

// ---------------- Fallback: round-2 fused kernel (ws too small) ------------
template <bool TRANSPOSED>
__global__ __launch_bounds__(256) void fff_fused(
    const float* __restrict__ x, const float* __restrict__ w_in,
    const float* __restrict__ w_out, float* __restrict__ out) {
    const int wave  = threadIdx.x >> 6;
    const int lane  = threadIdx.x & 63;
    const int token = blockIdx.x * 4 + wave;
    const float4* xrow = (const float4*)(x + (size_t)token * D_IN);
    float xf[32];
#pragma unroll
    for (int c = 0; c < 8; c++) {
        float4 xc = xrow[lane + 64 * c];
        xf[c * 4 + 0] = xc.x; xf[c * 4 + 1] = xc.y;
        xf[c * 4 + 2] = xc.z; xf[c * 4 + 3] = xc.w;
    }
    float acc[32];
#pragma unroll
    for (int k = 0; k < 32; k++) acc[k] = 0.f;
    int cur = 0;
#pragma unroll
    for (int l = 0; l < DEPTHP1; l++) {
        const float4* wrow = (const float4*)(w_in + (size_t)cur * D_IN);
        float part = 0.f;
#pragma unroll
        for (int c = 0; c < 8; c++) {
            float4 wc = wrow[lane + 64 * c];
            part += wc.x * xf[c * 4 + 0]; part += wc.y * xf[c * 4 + 1];
            part += wc.z * xf[c * 4 + 2]; part += wc.w * xf[c * 4 + 3];
        }
#pragma unroll
        for (int off = 32; off >= 1; off >>= 1) part += __shfl_xor(part, off, 64);
        const float score = part;
        const float g = 0.5f * score * (1.0f + erff(score * 0.70710678118654752f));
        if (TRANSPOSED) {
            const float4* orow = (const float4*)(w_out + (size_t)cur * D_OUT);
#pragma unroll
            for (int c = 0; c < 8; c++) {
                float4 oc = orow[lane + 64 * c];
                acc[c * 4 + 0] += g * oc.x; acc[c * 4 + 1] += g * oc.y;
                acc[c * 4 + 2] += g * oc.z; acc[c * 4 + 3] += g * oc.w;
            }
        } else {
#pragma unroll
            for (int c = 0; c < 8; c++)
#pragma unroll
                for (int k = 0; k < 4; k++) {
                    const int j = (lane + 64 * c) * 4 + k;
                    acc[c * 4 + k] += g * w_out[(size_t)j * N_NODES + cur];
                }
        }
        cur = 2 * cur + 1 + (score >= 0.f ? 1 : 0);
    }
    float4* outrow = (float4*)(out + (size_t)token * D_OUT);
#pragma unroll
    for (int c = 0; c < 8; c++) {
        float4 o;
        o.x = acc[c * 4 + 0]; o.y = acc[c * 4 + 1];
        o.z = acc[c * 4 + 2]; o.w = acc[c * 4 + 3];
        outrow[lane + 64 * c] = o;
    }
}

extern "C" void kernel_launch(void* const* d_in, const int* in_sizes, int n_in,
                              void* d_out, int out_size, void* d_ws, size_t ws_size,
                              hipStream_t stream) {
    (void)in_sizes; (void)n_in; (void)out_size;
    const float* x     = (const float*)d_in[0];
    const float* w_in  = (const float*)d_in[1];
    const float* w_out = (const float*)d_in[2];
    float* out = (float*)d_out;

    const size_t wt_bytes   = (size_t)N_NODES * D_OUT * sizeof(float);   // 33.546 MB
    const size_t g_bytes    = (size_t)N_TOK * DEPTHP1 * sizeof(float);   // 393 KB
    const size_t leaf_bytes = (size_t)N_TOK * sizeof(int);
    const size_t ord_bytes  = (size_t)N_TOK * sizeof(int);
    const size_t hist_bytes = (size_t)N_LEAF * sizeof(int);
    const size_t cnt_bytes  = (size_t)N_LEAF * sizeof(int);
    const size_t offs_bytes = (size_t)(N_LEAF + 1) * sizeof(int);
    const size_t need = wt_bytes + g_bytes + leaf_bytes + ord_bytes +
                        hist_bytes + cnt_bytes + offs_bytes + 64;

    if (ws_size >= need) {
        char* p = (char*)d_ws;
        float* w_out_t = (float*)p;  p += wt_bytes;
        float* g_all   = (float*)p;  p += g_bytes;
        int*   leaf    = (int*)p;    p += leaf_bytes;
        int*   order   = (int*)p;    p += ord_bytes;
        int*   hist    = (int*)p;    p += hist_bytes;   // hist+cnt contiguous
        int*   cnt     = (int*)p;    p += cnt_bytes;
        int*   offsets = (int*)p;

        init_counts<<<(2 * N_LEAF + 255) / 256, 256, 0, stream>>>(hist);
        transpose_wout64<<<dim3((N_NODES + 63) / 64, D_OUT / 64), dim3(64, 4),
                           0, stream>>>(w_out, w_out_t);
        phaseA<<<N_TOK / 4, 256, 0, stream>>>(x, w_in, g_all, leaf, hist);
        scan2048<<<1, 256, 0, stream>>>(hist, offsets);
        scatter_tokens<<<N_TOK / 256, 256, 0, stream>>>(leaf, offsets, cnt, order);
        phaseB<<<N_LEAF, 256, 0, stream>>>(w_out_t, g_all, order, offsets, out);
    } else if (ws_size >= wt_bytes) {
        float* w_out_t = (float*)d_ws;
        transpose_wout64<<<dim3((N_NODES + 63) / 64, D_OUT / 64), dim3(64, 4),
                           0, stream>>>(w_out, w_out_t);
        fff_fused<true><<<N_TOK / 4, 256, 0, stream>>>(x, w_in, w_out_t, out);
    } else {
        fff_fused<false><<<N_TOK / 4, 256, 0, stream>>>(x, w_in, w_out, out);
    }
}

// Round 4
// 254.218 us; speedup vs baseline: 2.2956x; 2.2956x over previous
//
#include <hip/hip_runtime.h>

// FFF tree-routing MLP, MI355X — fp32 I/O. Round 4: fix phaseB scratch spill.
//
// R3 post-mortem: phaseB had VGPR=28 + WRITE_SIZE=913MB (13x output) because
// acc[8][8] was indexed by a runtime-bounded loop -> spilled to scratch.
// Fix: all tt-loops are compile-time 8-wide; pad slots get g=0; stores guarded.
// Plus: scatter also produces g_sorted[pos][12] (contiguous g reads in phaseB),
// and phaseB leaf index is XCD-swizzled so each XCD's L2 caches one contiguous
// 256-leaf subtree slice of w_out_T (~3.5 MB, L2-resident).

#define D_IN    2048
#define D_OUT   2048
#define DEPTHP1 12
#define N_NODES 4095
#define N_TOK   8192
#define N_LEAF  2048

// ---------------- K1: transpose w_out [D_OUT, N_NODES] -> [N_NODES, D_OUT] --
__global__ __launch_bounds__(256) void transpose_wout64(
    const float* __restrict__ in, float* __restrict__ out) {
    __shared__ float tile[64][65];
    const int n0 = blockIdx.x * 64;
    const int j0 = blockIdx.y * 64;
    const int tx = threadIdx.x;       // 0..63
    const int ty = threadIdx.y;       // 0..3
    const int n = n0 + tx;
#pragma unroll
    for (int k = 0; k < 16; k++) {
        const int r = ty * 16 + k;    // 0..63
        if (n < N_NODES) tile[r][tx] = in[(size_t)(j0 + r) * N_NODES + n];
    }
    __syncthreads();
#pragma unroll
    for (int k = 0; k < 16; k++) {
        const int r = ty * 16 + k;
        const int nn = n0 + r;
        if (nn < N_NODES) out[(size_t)nn * D_OUT + (j0 + tx)] = tile[tx][r];
    }
}

// ---------------- K2: phase A — path + gelu(logit) per token ---------------
__global__ __launch_bounds__(256, 4) void phaseA(
    const float* __restrict__ x,      // [N_TOK, D_IN]
    const float* __restrict__ w_in,   // [N_NODES, D_IN]
    float* __restrict__ g_all,        // [N_TOK, 12]
    int* __restrict__ leaf,           // [N_TOK]
    int* __restrict__ hist) {         // [N_LEAF]
    const int wave  = threadIdx.x >> 6;
    const int lane  = threadIdx.x & 63;
    const int token = blockIdx.x * 4 + wave;

    const float4* xrow = (const float4*)(x + (size_t)token * D_IN);
    float xf[32];
#pragma unroll
    for (int c = 0; c < 8; c++) {
        float4 xc = xrow[lane + 64 * c];
        xf[c * 4 + 0] = xc.x;
        xf[c * 4 + 1] = xc.y;
        xf[c * 4 + 2] = xc.z;
        xf[c * 4 + 3] = xc.w;
    }

    int cur = 0;
    int leafid = 0;
#pragma unroll
    for (int l = 0; l < DEPTHP1; l++) {
        const float4* wrow = (const float4*)(w_in + (size_t)cur * D_IN);
        float part = 0.f;
#pragma unroll
        for (int c = 0; c < 8; c++) {
            float4 wc = wrow[lane + 64 * c];
            part += wc.x * xf[c * 4 + 0];
            part += wc.y * xf[c * 4 + 1];
            part += wc.z * xf[c * 4 + 2];
            part += wc.w * xf[c * 4 + 3];
        }
#pragma unroll
        for (int off = 32; off >= 1; off >>= 1)
            part += __shfl_xor(part, off, 64);
        const float score = part;
        const float g = 0.5f * score * (1.0f + erff(score * 0.70710678118654752f));
        if (lane == 0) g_all[token * DEPTHP1 + l] = g;
        if (l == DEPTHP1 - 1) leafid = cur - (N_LEAF - 1);  // cur in [2047,4094]
        cur = 2 * cur + 1 + (score >= 0.f ? 1 : 0);
    }
    if (lane == 0) {
        leaf[token] = leafid;
        atomicAdd(&hist[leafid], 1);
    }
}

// ---------------- K3: zero hist + cnt (contiguous 2*N_LEAF ints) -----------
__global__ __launch_bounds__(256) void init_counts(int* __restrict__ p) {
    const int i = blockIdx.x * 256 + threadIdx.x;
    if (i < 2 * N_LEAF) p[i] = 0;
}

// ---------------- K4: exclusive scan over 2048 bins ------------------------
__global__ __launch_bounds__(256) void scan2048(
    const int* __restrict__ hist, int* __restrict__ offsets /*[2049]*/) {
    __shared__ int vals[N_LEAF];
    __shared__ int partial[256];
    const int t = threadIdx.x;
    int sum = 0;
#pragma unroll
    for (int k = 0; k < 8; k++) {
        const int v = hist[t * 8 + k];
        vals[t * 8 + k] = v;
        sum += v;
    }
    partial[t] = sum;
    __syncthreads();
    for (int off = 1; off < 256; off <<= 1) {
        const int v  = partial[t];
        const int vo = (t >= off) ? partial[t - off] : 0;
        __syncthreads();
        partial[t] = v + vo;
        __syncthreads();
    }
    int base = (t > 0) ? partial[t - 1] : 0;
#pragma unroll
    for (int k = 0; k < 8; k++) {
        offsets[t * 8 + k] = base;
        base += vals[t * 8 + k];
    }
    if (t == 255) offsets[N_LEAF] = base;  // == N_TOK
}

// ---------------- K5: scatter tokens + g into leaf-sorted order ------------
__global__ __launch_bounds__(256) void scatter_tokens(
    const int* __restrict__ leaf, const int* __restrict__ offsets,
    int* __restrict__ cnt, const float* __restrict__ g_all,
    int* __restrict__ order, float* __restrict__ g_sorted) {
    const int t = blockIdx.x * 256 + threadIdx.x;
    if (t < N_TOK) {
        const int lf = leaf[t];
        const int pos = offsets[lf] + atomicAdd(&cnt[lf], 1);
        order[pos] = t;
#pragma unroll
        for (int l = 0; l < DEPTHP1; l++)
            g_sorted[(size_t)pos * DEPTHP1 + l] = g_all[(size_t)t * DEPTHP1 + l];
    }
}

// ---------------- K6: phase B — leaf-grouped output accumulation -----------
__global__ __launch_bounds__(256, 2) void phaseB(
    const float* __restrict__ w_out_t,  // [N_NODES, D_OUT]
    const float* __restrict__ g_sorted, // [N_TOK, 12] leaf-sorted
    const int* __restrict__ order,      // [N_TOK]
    const int* __restrict__ offsets,    // [N_LEAF+1]
    float* __restrict__ out) {          // [N_TOK, D_OUT]
    // XCD swizzle: XCD k (= blockIdx%8) gets contiguous leaves [k*256,(k+1)*256)
    const int lf = ((blockIdx.x & 7) << 8) | (blockIdx.x >> 3);
    const int start = offsets[lf];
    const int end   = offsets[lf + 1];
    if (start == end) return;
    const int t = threadIdx.x;           // owns cols [8t, 8t+8)

    int nodes[DEPTHP1];
    const int L = lf + N_LEAF;           // 1-based leaf heap index
#pragma unroll
    for (int l = 0; l < DEPTHP1; l++) nodes[l] = (L >> (DEPTHP1 - 1 - l)) - 1;

    for (int cs = start; cs < end; cs += 8) {
        const int T = end - cs;          // effective count this chunk: min(T,8)
        float acc[8][8];
#pragma unroll
        for (int tt = 0; tt < 8; tt++)
#pragma unroll
            for (int k = 0; k < 8; k++) acc[tt][k] = 0.f;

#pragma unroll
        for (int l = 0; l < DEPTHP1; l++) {
            const float4* wr = (const float4*)(w_out_t + (size_t)nodes[l] * D_OUT);
            const float4 w0 = wr[t * 2 + 0];
            const float4 w1 = wr[t * 2 + 1];
#pragma unroll
            for (int tt = 0; tt < 8; tt++) {
                const float g = (tt < T)
                    ? g_sorted[(size_t)(cs + tt) * DEPTHP1 + l] : 0.f;
                acc[tt][0] += g * w0.x; acc[tt][1] += g * w0.y;
                acc[tt][2] += g * w0.z; acc[tt][3] += g * w0.w;
                acc[tt][4] += g * w1.x; acc[tt][5] += g * w1.y;
                acc[tt][6] += g * w1.z; acc[tt][7] += g * w1.w;
            }
        }
#pragma unroll
        for (int tt = 0; tt < 8; tt++) {
            if (tt < T) {
                const int tok = order[cs + tt];
                float4* po = (float4*)(out + (size_t)tok * D_OUT + t * 8);
                float4 o0, o1;
                o0.x = acc[tt][0]; o0.y = acc[tt][1];
                o0.z = acc[tt][2]; o0.w = acc[tt][3];
                o1.x = acc[tt][4]; o1.y = acc[tt][5];
                o1.z = acc[tt][6]; o1.w = acc[tt][7];
                po[0] = o0; po[1] = o1;
            }
        }
    }
}

// ---------------- Fallback: round-2 fused kernel (ws too small) ------------
template <bool TRANSPOSED>
__global__ __launch_bounds__(256) void fff_fused(
    const float* __restrict__ x, const float* __restrict__ w_in,
    const float* __restrict__ w_out, float* __restrict__ out) {
    const int wave  = threadIdx.x >> 6;
    const int lane  = threadIdx.x & 63;
    const int token = blockIdx.x * 4 + wave;
    const float4* xrow = (const float4*)(x + (size_t)token * D_IN);
    float xf[32];
#pragma unroll
    for (int c = 0; c < 8; c++) {
        float4 xc = xrow[lane + 64 * c];
        xf[c * 4 + 0] = xc.x; xf[c * 4 + 1] = xc.y;
        xf[c * 4 + 2] = xc.z; xf[c * 4 + 3] = xc.w;
    }
    float acc[32];
#pragma unroll
    for (int k = 0; k < 32; k++) acc[k] = 0.f;
    int cur = 0;
#pragma unroll
    for (int l = 0; l < DEPTHP1; l++) {
        const float4* wrow = (const float4*)(w_in + (size_t)cur * D_IN);
        float part = 0.f;
#pragma unroll
        for (int c = 0; c < 8; c++) {
            float4 wc = wrow[lane + 64 * c];
            part += wc.x * xf[c * 4 + 0]; part += wc.y * xf[c * 4 + 1];
            part += wc.z * xf[c * 4 + 2]; part += wc.w * xf[c * 4 + 3];
        }
#pragma unroll
        for (int off = 32; off >= 1; off >>= 1) part += __shfl_xor(part, off, 64);
        const float score = part;
        const float g = 0.5f * score * (1.0f + erff(score * 0.70710678118654752f));
        if (TRANSPOSED) {
            const float4* orow = (const float4*)(w_out + (size_t)cur * D_OUT);
#pragma unroll
            for (int c = 0; c < 8; c++) {
                float4 oc = orow[lane + 64 * c];
                acc[c * 4 + 0] += g * oc.x; acc[c * 4 + 1] += g * oc.y;
                acc[c * 4 + 2] += g * oc.z; acc[c * 4 + 3] += g * oc.w;
            }
        } else {
#pragma unroll
            for (int c = 0; c < 8; c++)
#pragma unroll
                for (int k = 0; k < 4; k++) {
                    const int j = (lane + 64 * c) * 4 + k;
                    acc[c * 4 + k] += g * w_out[(size_t)j * N_NODES + cur];
                }
        }
        cur = 2 * cur + 1 + (score >= 0.f ? 1 : 0);
    }
    float4* outrow = (float4*)(out + (size_t)token * D_OUT);
#pragma unroll
    for (int c = 0; c < 8; c++) {
        float4 o;
        o.x = acc[c * 4 + 0]; o.y = acc[c * 4 + 1];
        o.z = acc[c * 4 + 2]; o.w = acc[c * 4 + 3];
        outrow[lane + 64 * c] = o;
    }
}

extern "C" void kernel_launch(void* const* d_in, const int* in_sizes, int n_in,
                              void* d_out, int out_size, void* d_ws, size_t ws_size,
                              hipStream_t stream) {
    (void)in_sizes; (void)n_in; (void)out_size;
    const float* x     = (const float*)d_in[0];
    const float* w_in  = (const float*)d_in[1];
    const float* w_out = (const float*)d_in[2];
    float* out = (float*)d_out;

    const size_t wt_bytes   = (size_t)N_NODES * D_OUT * sizeof(float);   // 33.546 MB
    const size_t g_bytes    = (size_t)N_TOK * DEPTHP1 * sizeof(float);   // 393 KB
    const size_t leaf_bytes = (size_t)N_TOK * sizeof(int);
    const size_t ord_bytes  = (size_t)N_TOK * sizeof(int);
    const size_t hist_bytes = (size_t)N_LEAF * sizeof(int);
    const size_t cnt_bytes  = (size_t)N_LEAF * sizeof(int);
    const size_t offs_bytes = (size_t)(N_LEAF + 1) * sizeof(int);
    const size_t gs_bytes   = g_bytes;                                   // g_sorted
    const size_t need = wt_bytes + g_bytes + leaf_bytes + ord_bytes +
                        hist_bytes + cnt_bytes + offs_bytes + gs_bytes + 64;

    if (ws_size >= need) {
        char* p = (char*)d_ws;
        float* w_out_t  = (float*)p;  p += wt_bytes;
        float* g_all    = (float*)p;  p += g_bytes;
        int*   leaf     = (int*)p;    p += leaf_bytes;
        int*   order    = (int*)p;    p += ord_bytes;
        int*   hist     = (int*)p;    p += hist_bytes;   // hist+cnt contiguous
        int*   cnt      = (int*)p;    p += cnt_bytes;
        int*   offsets  = (int*)p;    p += offs_bytes;
        float* g_sorted = (float*)p;

        init_counts<<<(2 * N_LEAF + 255) / 256, 256, 0, stream>>>(hist);
        transpose_wout64<<<dim3((N_NODES + 63) / 64, D_OUT / 64), dim3(64, 4),
                           0, stream>>>(w_out, w_out_t);
        phaseA<<<N_TOK / 4, 256, 0, stream>>>(x, w_in, g_all, leaf, hist);
        scan2048<<<1, 256, 0, stream>>>(hist, offsets);
        scatter_tokens<<<N_TOK / 256, 256, 0, stream>>>(leaf, offsets, cnt,
                                                        g_all, order, g_sorted);
        phaseB<<<N_LEAF, 256, 0, stream>>>(w_out_t, g_sorted, order, offsets, out);
    } else if (ws_size >= wt_bytes) {
        float* w_out_t = (float*)d_ws;
        transpose_wout64<<<dim3((N_NODES + 63) / 64, D_OUT / 64), dim3(64, 4),
                           0, stream>>>(w_out, w_out_t);
        fff_fused<true><<<N_TOK / 4, 256, 0, stream>>>(x, w_in, w_out_t, out);
    } else {
        fff_fused<false><<<N_TOK / 4, 256, 0, stream>>>(x, w_in, w_out, out);
    }
}

// Round 5
// 232.310 us; speedup vs baseline: 2.5121x; 1.0943x over previous
//
#include <hip/hip_runtime.h>

// FFF tree-routing MLP, MI355X — fp32 I/O. Round 5: phaseA x-in-LDS.
//
// R4 post-mortem: phaseA VGPR=36 => compiler rematerialized the x-row loads
// (xf[32] cannot live in 36 regs) — x was re-fetched from global EVERY level,
// putting 2 dependent global loads on each level's critical path. Fix: stage
// x in a wave-private 8KB LDS slice (32KB/block -> 5 blocks/CU = 20 waves/CU);
// per level only the w_in row load touches global. Dot uses 4 independent
// partial sums (shorter FMA chain); `cur` advances before gelu so next-level
// loads issue while erff computes.

#define D_IN    2048
#define D_OUT   2048
#define DEPTHP1 12
#define N_NODES 4095
#define N_TOK   8192
#define N_LEAF  2048

// ---------------- K1: transpose w_out [D_OUT, N_NODES] -> [N_NODES, D_OUT] --
__global__ __launch_bounds__(256) void transpose_wout64(
    const float* __restrict__ in, float* __restrict__ out) {
    __shared__ float tile[64][65];
    const int n0 = blockIdx.x * 64;
    const int j0 = blockIdx.y * 64;
    const int tx = threadIdx.x;       // 0..63
    const int ty = threadIdx.y;       // 0..3
    const int n = n0 + tx;
#pragma unroll
    for (int k = 0; k < 16; k++) {
        const int r = ty * 16 + k;    // 0..63
        if (n < N_NODES) tile[r][tx] = in[(size_t)(j0 + r) * N_NODES + n];
    }
    __syncthreads();
#pragma unroll
    for (int k = 0; k < 16; k++) {
        const int r = ty * 16 + k;
        const int nn = n0 + r;
        if (nn < N_NODES) out[(size_t)nn * D_OUT + (j0 + tx)] = tile[tx][r];
    }
}

// ---------------- K2: phase A — path + gelu(logit) per token ---------------
__global__ __launch_bounds__(256) void phaseA(
    const float* __restrict__ x,      // [N_TOK, D_IN]
    const float* __restrict__ w_in,   // [N_NODES, D_IN]
    float* __restrict__ g_all,        // [N_TOK, 12]
    int* __restrict__ leaf,           // [N_TOK]
    int* __restrict__ hist) {         // [N_LEAF]
    extern __shared__ float xs[];     // 4 waves x 2048 floats = 32 KB
    const int wave  = threadIdx.x >> 6;
    const int lane  = threadIdx.x & 63;
    const int token = blockIdx.x * 4 + wave;

    // Stage this token's x row into the wave-private LDS slice (once).
    float4* xw = (float4*)(xs) + wave * (D_IN / 4);
    const float4* xrow = (const float4*)(x + (size_t)token * D_IN);
#pragma unroll
    for (int c = 0; c < 8; c++) xw[lane + 64 * c] = xrow[lane + 64 * c];
    // Same-wave produce->consume; compiler inserts lgkmcnt wait. No barrier.

    int cur = 0;
#pragma unroll
    for (int l = 0; l < DEPTHP1; l++) {
        const float4* wrow = (const float4*)(w_in + (size_t)cur * D_IN);
        float p0 = 0.f, p1 = 0.f, p2 = 0.f, p3 = 0.f;
#pragma unroll
        for (int c = 0; c < 8; c++) {
            const float4 wc = wrow[lane + 64 * c];
            const float4 xc = xw[lane + 64 * c];
            float* p = (c < 2) ? &p0 : (c < 4) ? &p1 : (c < 6) ? &p2 : &p3;
            *p += wc.x * xc.x + wc.y * xc.y + wc.z * xc.z + wc.w * xc.w;
        }
        float part = (p0 + p1) + (p2 + p3);
#pragma unroll
        for (int off = 32; off >= 1; off >>= 1)
            part += __shfl_xor(part, off, 64);
        const float score = part;
        // Advance the path first: next-level loads depend only on `cur`.
        cur = 2 * cur + 1 + (score >= 0.f ? 1 : 0);
        const float g = 0.5f * score * (1.0f + erff(score * 0.70710678118654752f));
        if (lane == 0) g_all[token * DEPTHP1 + l] = g;
    }
    if (lane == 0) {
        const int leafid = ((cur - 1) >> 1) - (N_LEAF - 1);  // level-11 node id
        leaf[token] = leafid;
        atomicAdd(&hist[leafid], 1);
    }
}

// ---------------- K3: zero hist + cnt (contiguous 2*N_LEAF ints) -----------
__global__ __launch_bounds__(256) void init_counts(int* __restrict__ p) {
    const int i = blockIdx.x * 256 + threadIdx.x;
    if (i < 2 * N_LEAF) p[i] = 0;
}

// ---------------- K4: exclusive scan over 2048 bins ------------------------
__global__ __launch_bounds__(256) void scan2048(
    const int* __restrict__ hist, int* __restrict__ offsets /*[2049]*/) {
    __shared__ int vals[N_LEAF];
    __shared__ int partial[256];
    const int t = threadIdx.x;
    int sum = 0;
#pragma unroll
    for (int k = 0; k < 8; k++) {
        const int v = hist[t * 8 + k];
        vals[t * 8 + k] = v;
        sum += v;
    }
    partial[t] = sum;
    __syncthreads();
    for (int off = 1; off < 256; off <<= 1) {
        const int v  = partial[t];
        const int vo = (t >= off) ? partial[t - off] : 0;
        __syncthreads();
        partial[t] = v + vo;
        __syncthreads();
    }
    int base = (t > 0) ? partial[t - 1] : 0;
#pragma unroll
    for (int k = 0; k < 8; k++) {
        offsets[t * 8 + k] = base;
        base += vals[t * 8 + k];
    }
    if (t == 255) offsets[N_LEAF] = base;  // == N_TOK
}

// ---------------- K5: scatter tokens + g into leaf-sorted order ------------
__global__ __launch_bounds__(256) void scatter_tokens(
    const int* __restrict__ leaf, const int* __restrict__ offsets,
    int* __restrict__ cnt, const float* __restrict__ g_all,
    int* __restrict__ order, float* __restrict__ g_sorted) {
    const int t = blockIdx.x * 256 + threadIdx.x;
    if (t < N_TOK) {
        const int lf = leaf[t];
        const int pos = offsets[lf] + atomicAdd(&cnt[lf], 1);
        order[pos] = t;
#pragma unroll
        for (int l = 0; l < DEPTHP1; l++)
            g_sorted[(size_t)pos * DEPTHP1 + l] = g_all[(size_t)t * DEPTHP1 + l];
    }
}

// ---------------- K6: phase B — leaf-grouped output accumulation -----------
__global__ __launch_bounds__(256, 2) void phaseB(
    const float* __restrict__ w_out_t,  // [N_NODES, D_OUT]
    const float* __restrict__ g_sorted, // [N_TOK, 12] leaf-sorted
    const int* __restrict__ order,      // [N_TOK]
    const int* __restrict__ offsets,    // [N_LEAF+1]
    float* __restrict__ out) {          // [N_TOK, D_OUT]
    // XCD swizzle: XCD k (= blockIdx%8) gets contiguous leaves [k*256,(k+1)*256)
    const int lf = ((blockIdx.x & 7) << 8) | (blockIdx.x >> 3);
    const int start = offsets[lf];
    const int end   = offsets[lf + 1];
    if (start == end) return;
    const int t = threadIdx.x;           // owns cols [8t, 8t+8)

    int nodes[DEPTHP1];
    const int L = lf + N_LEAF;           // 1-based leaf heap index
#pragma unroll
    for (int l = 0; l < DEPTHP1; l++) nodes[l] = (L >> (DEPTHP1 - 1 - l)) - 1;

    for (int cs = start; cs < end; cs += 8) {
        const int T = end - cs;          // effective count this chunk: min(T,8)
        float acc[8][8];
#pragma unroll
        for (int tt = 0; tt < 8; tt++)
#pragma unroll
            for (int k = 0; k < 8; k++) acc[tt][k] = 0.f;

#pragma unroll
        for (int l = 0; l < DEPTHP1; l++) {
            const float4* wr = (const float4*)(w_out_t + (size_t)nodes[l] * D_OUT);
            const float4 w0 = wr[t * 2 + 0];
            const float4 w1 = wr[t * 2 + 1];
#pragma unroll
            for (int tt = 0; tt < 8; tt++) {
                const float g = (tt < T)
                    ? g_sorted[(size_t)(cs + tt) * DEPTHP1 + l] : 0.f;
                acc[tt][0] += g * w0.x; acc[tt][1] += g * w0.y;
                acc[tt][2] += g * w0.z; acc[tt][3] += g * w0.w;
                acc[tt][4] += g * w1.x; acc[tt][5] += g * w1.y;
                acc[tt][6] += g * w1.z; acc[tt][7] += g * w1.w;
            }
        }
#pragma unroll
        for (int tt = 0; tt < 8; tt++) {
            if (tt < T) {
                const int tok = order[cs + tt];
                float4* po = (float4*)(out + (size_t)tok * D_OUT + t * 8);
                float4 o0, o1;
                o0.x = acc[tt][0]; o0.y = acc[tt][1];
                o0.z = acc[tt][2]; o0.w = acc[tt][3];
                o1.x = acc[tt][4]; o1.y = acc[tt][5];
                o1.z = acc[tt][6]; o1.w = acc[tt][7];
                po[0] = o0; po[1] = o1;
            }
        }
    }
}

// ---------------- Fallback: round-2 fused kernel (ws too small) ------------
template <bool TRANSPOSED>
__global__ __launch_bounds__(256) void fff_fused(
    const float* __restrict__ x, const float* __restrict__ w_in,
    const float* __restrict__ w_out, float* __restrict__ out) {
    const int wave  = threadIdx.x >> 6;
    const int lane  = threadIdx.x & 63;
    const int token = blockIdx.x * 4 + wave;
    const float4* xrow = (const float4*)(x + (size_t)token * D_IN);
    float xf[32];
#pragma unroll
    for (int c = 0; c < 8; c++) {
        float4 xc = xrow[lane + 64 * c];
        xf[c * 4 + 0] = xc.x; xf[c * 4 + 1] = xc.y;
        xf[c * 4 + 2] = xc.z; xf[c * 4 + 3] = xc.w;
    }
    float acc[32];
#pragma unroll
    for (int k = 0; k < 32; k++) acc[k] = 0.f;
    int cur = 0;
#pragma unroll
    for (int l = 0; l < DEPTHP1; l++) {
        const float4* wrow = (const float4*)(w_in + (size_t)cur * D_IN);
        float part = 0.f;
#pragma unroll
        for (int c = 0; c < 8; c++) {
            float4 wc = wrow[lane + 64 * c];
            part += wc.x * xf[c * 4 + 0]; part += wc.y * xf[c * 4 + 1];
            part += wc.z * xf[c * 4 + 2]; part += wc.w * xf[c * 4 + 3];
        }
#pragma unroll
        for (int off = 32; off >= 1; off >>= 1) part += __shfl_xor(part, off, 64);
        const float score = part;
        const float g = 0.5f * score * (1.0f + erff(score * 0.70710678118654752f));
        if (TRANSPOSED) {
            const float4* orow = (const float4*)(w_out + (size_t)cur * D_OUT);
#pragma unroll
            for (int c = 0; c < 8; c++) {
                float4 oc = orow[lane + 64 * c];
                acc[c * 4 + 0] += g * oc.x; acc[c * 4 + 1] += g * oc.y;
                acc[c * 4 + 2] += g * oc.z; acc[c * 4 + 3] += g * oc.w;
            }
        } else {
#pragma unroll
            for (int c = 0; c < 8; c++)
#pragma unroll
                for (int k = 0; k < 4; k++) {
                    const int j = (lane + 64 * c) * 4 + k;
                    acc[c * 4 + k] += g * w_out[(size_t)j * N_NODES + cur];
                }
        }
        cur = 2 * cur + 1 + (score >= 0.f ? 1 : 0);
    }
    float4* outrow = (float4*)(out + (size_t)token * D_OUT);
#pragma unroll
    for (int c = 0; c < 8; c++) {
        float4 o;
        o.x = acc[c * 4 + 0]; o.y = acc[c * 4 + 1];
        o.z = acc[c * 4 + 2]; o.w = acc[c * 4 + 3];
        outrow[lane + 64 * c] = o;
    }
}

extern "C" void kernel_launch(void* const* d_in, const int* in_sizes, int n_in,
                              void* d_out, int out_size, void* d_ws, size_t ws_size,
                              hipStream_t stream) {
    (void)in_sizes; (void)n_in; (void)out_size;
    const float* x     = (const float*)d_in[0];
    const float* w_in  = (const float*)d_in[1];
    const float* w_out = (const float*)d_in[2];
    float* out = (float*)d_out;

    const size_t wt_bytes   = (size_t)N_NODES * D_OUT * sizeof(float);   // 33.546 MB
    const size_t g_bytes    = (size_t)N_TOK * DEPTHP1 * sizeof(float);   // 393 KB
    const size_t leaf_bytes = (size_t)N_TOK * sizeof(int);
    const size_t ord_bytes  = (size_t)N_TOK * sizeof(int);
    const size_t hist_bytes = (size_t)N_LEAF * sizeof(int);
    const size_t cnt_bytes  = (size_t)N_LEAF * sizeof(int);
    const size_t offs_bytes = (size_t)(N_LEAF + 1) * sizeof(int);
    const size_t gs_bytes   = g_bytes;                                   // g_sorted
    const size_t need = wt_bytes + g_bytes + leaf_bytes + ord_bytes +
                        hist_bytes + cnt_bytes + offs_bytes + gs_bytes + 64;

    if (ws_size >= need) {
        char* p = (char*)d_ws;
        float* w_out_t  = (float*)p;  p += wt_bytes;
        float* g_all    = (float*)p;  p += g_bytes;
        int*   leaf     = (int*)p;    p += leaf_bytes;
        int*   order    = (int*)p;    p += ord_bytes;
        int*   hist     = (int*)p;    p += hist_bytes;   // hist+cnt contiguous
        int*   cnt      = (int*)p;    p += cnt_bytes;
        int*   offsets  = (int*)p;    p += offs_bytes;
        float* g_sorted = (float*)p;

        init_counts<<<(2 * N_LEAF + 255) / 256, 256, 0, stream>>>(hist);
        transpose_wout64<<<dim3((N_NODES + 63) / 64, D_OUT / 64), dim3(64, 4),
                           0, stream>>>(w_out, w_out_t);
        phaseA<<<N_TOK / 4, 256, 4 * D_IN * sizeof(float), stream>>>(
            x, w_in, g_all, leaf, hist);
        scan2048<<<1, 256, 0, stream>>>(hist, offsets);
        scatter_tokens<<<N_TOK / 256, 256, 0, stream>>>(leaf, offsets, cnt,
                                                        g_all, order, g_sorted);
        phaseB<<<N_LEAF, 256, 0, stream>>>(w_out_t, g_sorted, order, offsets, out);
    } else if (ws_size >= wt_bytes) {
        float* w_out_t = (float*)d_ws;
        transpose_wout64<<<dim3((N_NODES + 63) / 64, D_OUT / 64), dim3(64, 4),
                           0, stream>>>(w_out, w_out_t);
        fff_fused<true><<<N_TOK / 4, 256, 0, stream>>>(x, w_in, w_out_t, out);
    } else {
        fff_fused<false><<<N_TOK / 4, 256, 0, stream>>>(x, w_in, w_out, out);
    }
}